// Round 10
// baseline (581.756 us; speedup 1.0000x reference)
//
#include <hip/hip_runtime.h>
#include <math.h>

// GCN: 4x GCNConv (self-loops, sym-norm) + BN+GELU between, log_softmax at end.
// CSR (by dst) built per call; aggregation = atomic-free gather; aggregate on the
// narrow side of each layer (linearity); BN bias-cancellation drops b1..b3.
// R1: hierarchical scan, fused BN-stats, fused log_softmax. 806 -> 622 us.
// R4: dinv-prescale + unrolled gather. 622 -> 553 us.
// R6: bucket-sort CSR build, all writes coalesced. 553 -> 524 us.
// R7: count_kernel + N-scans deleted (per-bucket LDS degree count). 524 -> 450 us.
// R9: gemm rewrite. Old: 1 output/thread, 128 scalar loads each (VALUBusy 12%,
//     occupancy 26%, 55us = VMEM-issue-bound). New: (row, 4-col-group)/thread,
//     float4 H loads (16 FMA per load), float4 stores; BN-stats via shfl_xor
//     coset reduce + per-wave LDS atomics. L4 (FOUT=10): 2 thr/row, 5 cols each.

#define TPB 256
#define K_BUCK 256
#define CCHUNK 4096   // edges per chunk in C1/C2 (stage = 32 KB LDS)
#define DCAP 8192     // per-bucket CSR LDS capacity (32 KB); mean 6250, +24 sigma
constexpr float BN_EPS = 1e-5f;

#define SCHUNK 2048  // elements per scan block (256 thr x 8)

__global__ void scan_reduce_kernel(const int* __restrict__ in, int* __restrict__ bsum, int n) {
    int base = blockIdx.x * SCHUNK;
    int s = 0;
    for (int j = threadIdx.x; j < SCHUNK; j += TPB) {
        int i = base + j;
        s += (i < n) ? in[i] : 0;
    }
#pragma unroll
    for (int d = 32; d; d >>= 1) s += __shfl_down(s, d);
    __shared__ int ws[TPB / 64];
    if ((threadIdx.x & 63) == 0) ws[threadIdx.x >> 6] = s;
    __syncthreads();
    if (threadIdx.x == 0) {
        int t = 0;
        for (int w = 0; w < TPB / 64; ++w) t += ws[w];
        bsum[blockIdx.x] = t;
    }
}

// single wave: exclusive-scan bsum[0..nb)
__global__ void scan_bsum_kernel(int* __restrict__ bsum, int nb) {
    __shared__ int carry;
    int lane = threadIdx.x;
    if (lane == 0) carry = 0;
    __syncthreads();
    for (int base = 0; base < nb; base += 64) {
        int i = base + lane;
        int v = (i < nb) ? bsum[i] : 0;
        int incl = v;
#pragma unroll
        for (int d = 1; d < 64; d <<= 1) {
            int u = __shfl_up(incl, d);
            if (lane >= d) incl += u;
        }
        if (i < nb) bsum[i] = carry + incl - v;
        int tot = __shfl(incl, 63);
        __syncthreads();
        if (lane == 0) carry += tot;
        __syncthreads();
    }
}

// block-local scan + apply block prefix
__global__ void scan_apply_kernel(const int* __restrict__ in, const int* __restrict__ bsum,
                                  int* __restrict__ out, int n) {
    int base = blockIdx.x * SCHUNK;
    int tid = threadIdx.x;
    int lane = tid & 63, wave = tid >> 6;
    int i0 = base + tid * 8;
    int v[8];
    int tsum = 0;
#pragma unroll
    for (int k = 0; k < 8; ++k) {
        int i = i0 + k;
        v[k] = (i < n) ? in[i] : 0;
        tsum += v[k];
    }
    int incl = tsum;
#pragma unroll
    for (int d = 1; d < 64; d <<= 1) {
        int u = __shfl_up(incl, d);
        if (lane >= d) incl += u;
    }
    int lexcl = incl - tsum;
    __shared__ int wsum[TPB / 64];
    if (lane == 63) wsum[wave] = incl;
    __syncthreads();
    int wbase = 0;
    for (int w = 0; w < wave; ++w) wbase += wsum[w];
    int off = bsum[blockIdx.x] + wbase + lexcl;
#pragma unroll
    for (int k = 0; k < 8; ++k) {
        int i = i0 + k;
        if (i < n) out[i] = off;
        off += v[k];
    }
}

// ---------------- bucket-sort CSR build (all writes coalesced) ----------------

// C1: per-chunk histogram over K_BUCK dst-buckets -> hist[bucket * nb + chunk].
// Block 0 also zeroes the BN stats accumulators (runs well before any stats use).
__global__ void bucket_hist_kernel(const int* __restrict__ dst, int* __restrict__ hist,
                                   float* __restrict__ stats, int e, int n, int nb) {
    __shared__ int lh[K_BUCK];
    for (int i = threadIdx.x; i < K_BUCK; i += TPB) lh[i] = 0;
    if (blockIdx.x == 0)
        for (int i = threadIdx.x; i < 384; i += TPB) stats[i] = 0.0f;
    __syncthreads();
    int base = blockIdx.x * CCHUNK;
    int end = min(base + CCHUNK, e);
    int div = (n + K_BUCK - 1) / K_BUCK;
    for (int i = base + threadIdx.x; i < end; i += TPB) atomicAdd(&lh[dst[i] / div], 1);
    __syncthreads();
    for (int b = threadIdx.x; b < K_BUCK; b += TPB) hist[b * nb + blockIdx.x] = lh[b];
}

// C2: re-read chunk, group edges by bucket in LDS, flush runs to ebuf with
// sequential (coalesced) writes. hbase = exclusive scan of hist (bucket-major).
__global__ void bucket_scatter_kernel(const int* __restrict__ src, const int* __restrict__ dst,
                                      const int* __restrict__ hist, const int* __restrict__ hbase,
                                      int2* __restrict__ ebuf, int e, int n, int nb) {
    __shared__ int lbase[K_BUCK];  // global base of this (chunk,bucket) run
    __shared__ int eoff[K_BUCK];   // exclusive local offset of bucket in stage
    __shared__ int lcur[K_BUCK];   // local cursor
    __shared__ int2 stage[CCHUNK];
    int t = threadIdx.x;  // TPB == K_BUCK
    int blk = blockIdx.x;
    int c = hist[t * nb + blk];
    lbase[t] = hbase[t * nb + blk];
    lcur[t] = 0;
    eoff[t] = c;
    __syncthreads();
    for (int d = 1; d < K_BUCK; d <<= 1) {  // inclusive scan of counts
        int v = (t >= d) ? eoff[t - d] : 0;
        __syncthreads();
        eoff[t] += v;
        __syncthreads();
    }
    eoff[t] -= c;  // exclusive
    __syncthreads();
    int base = blk * CCHUNK;
    int end = min(base + CCHUNK, e);
    int div = (n + K_BUCK - 1) / K_BUCK;
    for (int i = base + t; i < end; i += TPB) {
        int d = dst[i];
        int b = d / div;
        int p = atomicAdd(&lcur[b], 1);
        stage[eoff[b] + p] = make_int2(src[i], d);
    }
    __syncthreads();
    int cnt_here = end - base;
    for (int j = t; j < cnt_here; j += TPB) {
        int2 e2 = stage[j];
        int b = e2.y / div;
        ebuf[lbase[b] + (j - eoff[b])] = e2;  // coalesced within runs
    }
}

// R7: per-bucket degree count (LDS atomics) + local wave scan -> offsets,
// dinv written coalesced. Global prefix at bucket boundary = hbase[b*nb] (free).
__global__ void bucket_offsets_kernel(const int2* __restrict__ ebuf, const int* __restrict__ hbase,
                                      int* __restrict__ offsets, float* __restrict__ dinv,
                                      int e, int n, int nb) {
    __shared__ int lcnt[512];
    __shared__ int lexc[512];
    int b = blockIdx.x;
    int div = (n + K_BUCK - 1) / K_BUCK;
    int lo = b * div;
    int hi = min(lo + div, n);
    int nloc = hi - lo;
    int ebeg = hbase[b * nb];
    int eend = (b == K_BUCK - 1) ? e : hbase[(b + 1) * nb];
    for (int i = threadIdx.x; i < 512; i += TPB) lcnt[i] = 0;
    __syncthreads();
    for (int j = ebeg + threadIdx.x; j < eend; j += TPB)
        atomicAdd(&lcnt[ebuf[j].y - lo], 1);
    __syncthreads();
    if (threadIdx.x < 64) {  // wave 0: exclusive scan of lcnt[0..512)
        int l = threadIdx.x;
        int base = l * 8;
        int v[8];
        int tsum = 0;
#pragma unroll
        for (int k = 0; k < 8; ++k) { v[k] = lcnt[base + k]; tsum += v[k]; }
        int incl = tsum;
#pragma unroll
        for (int d = 1; d < 64; d <<= 1) {
            int u = __shfl_up(incl, d);
            if (l >= d) incl += u;
        }
        int off = incl - tsum;
#pragma unroll
        for (int k = 0; k < 8; ++k) { lexc[base + k] = off; off += v[k]; }
    }
    __syncthreads();
    for (int i = threadIdx.x; i < nloc; i += TPB) {
        offsets[lo + i] = ebeg + lexc[i];
        dinv[lo + i] = rsqrtf((float)(lcnt[i] + 1));  // +1 = self loop
    }
    if (b == K_BUCK - 1 && threadIdx.x == 0) offsets[n] = e;
}

// D: one block per bucket; build the bucket's CSR segment in LDS via local
// cursors (offsets - segbase), then stream it out as full coalesced lines.
__global__ void csr_fill_kernel(const int2* __restrict__ ebuf, const int* __restrict__ hbase,
                                const int* __restrict__ offsets, int* __restrict__ csr_src,
                                int e, int n, int nb) {
    __shared__ int lcur[400];
    __shared__ int lcsr[DCAP];
    int b = blockIdx.x;
    int div = (n + K_BUCK - 1) / K_BUCK;
    int lo = b * div;
    int hi = min(lo + div, n);
    int ebeg = hbase[b * nb];
    int eend = (b == K_BUCK - 1) ? e : hbase[(b + 1) * nb];
    int segbase = offsets[lo];
    int seglen = eend - ebeg;
    for (int i = threadIdx.x; i < hi - lo; i += TPB) lcur[i] = offsets[lo + i] - segbase;
    __syncthreads();
    for (int j = ebeg + threadIdx.x; j < eend; j += TPB) {
        int2 e2 = ebuf[j];
        int p = atomicAdd(&lcur[e2.y - lo], 1);
        if (p < DCAP) lcsr[p] = e2.x;
        else csr_src[segbase + p] = e2.x;  // overflow guard (statistically never)
    }
    __syncthreads();
    int lim = min(seglen, DCAP);
    for (int j = threadIdx.x; j < lim; j += TPB) csr_src[segbase + j] = lcsr[j];
}

// ---------------- dense transforms (R9: row x 4-col tiles, float4 loads) ----------------

// Thread (row, cg) computes cols [cg*4, cg*4+4) of one row: FIN/4 float4 loads,
// 16 FMA per load, one float4 store. BN-stats (on unscaled acc) via shfl_xor
// coset reduce over lanes with equal lane%CG, then 8 LDS atomics per wave.
template <int FIN, int FOUT, bool STATS, bool DINV>
__global__ void gemm4_kernel(const float* __restrict__ H, const float* __restrict__ W,
                             float* __restrict__ O, float* __restrict__ stats,
                             const float* __restrict__ dinv, int n) {
    constexpr int CG = FOUT / 4;
    __shared__ float Ws[FIN * FOUT];
    __shared__ float sh[STATS ? 2 * FOUT : 1];
    for (int i = threadIdx.x; i < FIN * FOUT; i += blockDim.x) Ws[i] = W[i];
    if (STATS)
        for (int i = threadIdx.x; i < 2 * FOUT; i += blockDim.x) sh[i] = 0.0f;
    __syncthreads();
    int gid = blockIdx.x * blockDim.x + threadIdx.x;
    int row = gid / CG;
    int cg = gid % CG;   // == lane % CG (TPB and 64 are multiples of CG)
    int c0 = cg * 4;
    float4 acc = make_float4(0.f, 0.f, 0.f, 0.f);
    if (row < n) {
        const float4* h4 = (const float4*)(H + (size_t)row * FIN);
#pragma unroll
        for (int k = 0; k < FIN / 4; ++k) {
            float4 h = h4[k];
            const float* w0 = &Ws[(4 * k) * FOUT + c0];
            const float* w1 = w0 + FOUT;
            const float* w2 = w1 + FOUT;
            const float* w3 = w2 + FOUT;
            acc.x = fmaf(h.x, w0[0], acc.x); acc.y = fmaf(h.x, w0[1], acc.y);
            acc.z = fmaf(h.x, w0[2], acc.z); acc.w = fmaf(h.x, w0[3], acc.w);
            acc.x = fmaf(h.y, w1[0], acc.x); acc.y = fmaf(h.y, w1[1], acc.y);
            acc.z = fmaf(h.y, w1[2], acc.z); acc.w = fmaf(h.y, w1[3], acc.w);
            acc.x = fmaf(h.z, w2[0], acc.x); acc.y = fmaf(h.z, w2[1], acc.y);
            acc.z = fmaf(h.z, w2[2], acc.z); acc.w = fmaf(h.z, w2[3], acc.w);
            acc.x = fmaf(h.w, w3[0], acc.x); acc.y = fmaf(h.w, w3[1], acc.y);
            acc.z = fmaf(h.w, w3[2], acc.z); acc.w = fmaf(h.w, w3[3], acc.w);
        }
    }
    if (STATS) {
        float4 s = acc;
        float4 q = make_float4(acc.x * acc.x, acc.y * acc.y, acc.z * acc.z, acc.w * acc.w);
#pragma unroll
        for (int d = CG; d < 64; d <<= 1) {
            s.x += __shfl_xor(s.x, d); s.y += __shfl_xor(s.y, d);
            s.z += __shfl_xor(s.z, d); s.w += __shfl_xor(s.w, d);
            q.x += __shfl_xor(q.x, d); q.y += __shfl_xor(q.y, d);
            q.z += __shfl_xor(q.z, d); q.w += __shfl_xor(q.w, d);
        }
        int lane = threadIdx.x & 63;
        if (lane < CG) {
            int cc = lane * 4;
            atomicAdd(&sh[cc + 0], s.x); atomicAdd(&sh[cc + 1], s.y);
            atomicAdd(&sh[cc + 2], s.z); atomicAdd(&sh[cc + 3], s.w);
            atomicAdd(&sh[FOUT + cc + 0], q.x); atomicAdd(&sh[FOUT + cc + 1], q.y);
            atomicAdd(&sh[FOUT + cc + 2], q.z); atomicAdd(&sh[FOUT + cc + 3], q.w);
        }
    }
    if (row < n) {
        float sc = DINV ? dinv[row] : 1.0f;
        float4 o = make_float4(acc.x * sc, acc.y * sc, acc.z * sc, acc.w * sc);
        ((float4*)O)[(size_t)row * CG + cg] = o;
    }
    if (STATS) {
        __syncthreads();
        for (int i = threadIdx.x; i < 2 * FOUT; i += blockDim.x) atomicAdd(&stats[i], sh[i]);
    }
}

// L4: FIN=64 -> FOUT=10, prescaled by dinv. 2 threads/row, 5 cols each.
__global__ void gemm_l4_kernel(const float* __restrict__ H, const float* __restrict__ W,
                               float* __restrict__ O, const float* __restrict__ dinv, int n) {
    __shared__ float Ws[64 * 10];
    for (int i = threadIdx.x; i < 640; i += blockDim.x) Ws[i] = W[i];
    __syncthreads();
    int gid = blockIdx.x * blockDim.x + threadIdx.x;
    int row = gid >> 1;
    int c0 = (gid & 1) * 5;
    if (row >= n) return;
    float acc[5] = {0.f, 0.f, 0.f, 0.f, 0.f};
    const float4* h4 = (const float4*)(H + (size_t)row * 64);
#pragma unroll
    for (int k = 0; k < 16; ++k) {
        float4 h = h4[k];
        const float* w0 = &Ws[(4 * k) * 10 + c0];
#pragma unroll
        for (int c = 0; c < 5; ++c) {
            acc[c] = fmaf(h.x, w0[c], acc[c]);
            acc[c] = fmaf(h.y, w0[10 + c], acc[c]);
            acc[c] = fmaf(h.z, w0[20 + c], acc[c]);
            acc[c] = fmaf(h.w, w0[30 + c], acc[c]);
        }
    }
    float sc = dinv[row];
#pragma unroll
    for (int c = 0; c < 5; ++c) O[(size_t)row * 10 + c0 + c] = acc[c] * sc;
}

// ---------------- aggregation ----------------

// Gather-aggregate over dinv-PRESCALED table T' (T'[u] = T[u]*dinv[u]):
//   out[node] = dinv[node] * (sum_{u in nbr} T'[u] + T'[node])
// Inner loop is pure gather+add, unrolled x4 for MLP. F%4==0: F/4 lanes/node.
template <int F, bool STATS>
__global__ void agg4_kernel(const float* __restrict__ T, float* __restrict__ A,
                            const float* __restrict__ dinv, const int* __restrict__ offsets,
                            const int* __restrict__ csr_src, float* __restrict__ stats, int n) {
    constexpr int G = F / 4;
    __shared__ float sh[STATS ? 2 * F : 1];
    if (STATS) {
        for (int i = threadIdx.x; i < 2 * F; i += blockDim.x) sh[i] = 0.0f;
        __syncthreads();
    }
    const float4* T4 = (const float4*)T;
    float4 ss = {0, 0, 0, 0}, s2 = {0, 0, 0, 0};
    int lane0 = -1;
    int total = n * G;
    int stride = gridDim.x * blockDim.x;  // % G == 0 since TPB % G == 0
    for (int idx = blockIdx.x * blockDim.x + threadIdx.x; idx < total; idx += stride) {
        int node = idx / G;
        int lane = idx % G;
        float4 acc = T4[(size_t)node * G + lane];  // self term (prescaled)
        int s = offsets[node], e = offsets[node + 1];
        int j = s;
        for (; j + 3 < e; j += 4) {
            int u0 = csr_src[j], u1 = csr_src[j + 1], u2 = csr_src[j + 2], u3 = csr_src[j + 3];
            float4 t0 = T4[(size_t)u0 * G + lane];
            float4 t1 = T4[(size_t)u1 * G + lane];
            float4 t2 = T4[(size_t)u2 * G + lane];
            float4 t3 = T4[(size_t)u3 * G + lane];
            acc.x += (t0.x + t1.x) + (t2.x + t3.x);
            acc.y += (t0.y + t1.y) + (t2.y + t3.y);
            acc.z += (t0.z + t1.z) + (t2.z + t3.z);
            acc.w += (t0.w + t1.w) + (t2.w + t3.w);
        }
        for (; j < e; ++j) {
            int u = csr_src[j];
            float4 t = T4[(size_t)u * G + lane];
            acc.x += t.x; acc.y += t.y; acc.z += t.z; acc.w += t.w;
        }
        float di = dinv[node];
        acc.x *= di; acc.y *= di; acc.z *= di; acc.w *= di;
        ((float4*)A)[(size_t)idx] = acc;
        if (STATS) {
            ss.x += acc.x; ss.y += acc.y; ss.z += acc.z; ss.w += acc.w;
            s2.x = fmaf(acc.x, acc.x, s2.x); s2.y = fmaf(acc.y, acc.y, s2.y);
            s2.z = fmaf(acc.z, acc.z, s2.z); s2.w = fmaf(acc.w, acc.w, s2.w);
            lane0 = lane;
        }
    }
    if (STATS) {
        if (lane0 >= 0) {
            atomicAdd(&sh[lane0 * 4 + 0], ss.x); atomicAdd(&sh[lane0 * 4 + 1], ss.y);
            atomicAdd(&sh[lane0 * 4 + 2], ss.z); atomicAdd(&sh[lane0 * 4 + 3], ss.w);
            atomicAdd(&sh[F + lane0 * 4 + 0], s2.x); atomicAdd(&sh[F + lane0 * 4 + 1], s2.y);
            atomicAdd(&sh[F + lane0 * 4 + 2], s2.z); atomicAdd(&sh[F + lane0 * 4 + 3], s2.w);
        }
        __syncthreads();
        for (int i = threadIdx.x; i < 2 * F; i += blockDim.x) atomicAdd(&stats[i], sh[i]);
    }
}

// Final layer: aggregate prescaled F=10 (16 lanes/node) + b4 + log_softmax.
__global__ void agg_lsm_kernel(const float* __restrict__ T, const float* __restrict__ dinv,
                               const int* __restrict__ offsets, const int* __restrict__ csr_src,
                               const float* __restrict__ b4, float* __restrict__ out, int n) {
    int idx = blockIdx.x * blockDim.x + threadIdx.x;
    int node = idx >> 4;
    int lane = idx & 15;
    if (node >= n) return;
    bool act = lane < 10;
    float acc = act ? T[(size_t)node * 10 + lane] : 0.0f;  // self (prescaled)
    int s = offsets[node], e = offsets[node + 1];
    int j = s;
    for (; j + 1 < e; j += 2) {
        int u0 = csr_src[j], u1 = csr_src[j + 1];
        float t0 = act ? T[(size_t)u0 * 10 + lane] : 0.0f;
        float t1 = act ? T[(size_t)u1 * 10 + lane] : 0.0f;
        acc += t0 + t1;
    }
    if (j < e) {
        int u = csr_src[j];
        if (act) acc += T[(size_t)u * 10 + lane];
    }
    float v = act ? fmaf(dinv[node], acc, b4[lane]) : -1e30f;
    float m = v;
#pragma unroll
    for (int d = 1; d < 16; d <<= 1) m = fmaxf(m, __shfl_xor(m, d));
    float ex = act ? expf(v - m) : 0.0f;
    float sum = ex;
#pragma unroll
    for (int d = 1; d < 16; d <<= 1) sum += __shfl_xor(sum, d);
    if (act) out[(size_t)node * 10 + lane] = v - m - logf(sum);
}

// ---------------- BN + GELU ----------------

// In-place BN (batch stats) + exact GELU; optional prescale by dinv (next-agg fusion).
template <int F, bool DINV>
__global__ void bn_gelu_kernel(float* __restrict__ V, const float* __restrict__ stats,
                               const float* __restrict__ g, const float* __restrict__ be,
                               const float* __restrict__ dinv, int n) {
    int i = blockIdx.x * blockDim.x + threadIdx.x;
    if (i >= n * F) return;
    int f = i % F;
    float inv_n = 1.0f / (float)n;
    float mu = stats[f] * inv_n;
    float var = stats[F + f] * inv_n - mu * mu;
    float sc = rsqrtf(var + BN_EPS) * g[f];
    float shf = be[f] - mu * sc;
    float x = fmaf(V[i], sc, shf);
    float y = 0.5f * x * (1.0f + erff(x * 0.70710678118654752f));
    V[i] = DINV ? y * dinv[i / F] : y;
}

static inline int cdiv(long long a, int b) { return (int)((a + b - 1) / b); }

extern "C" void kernel_launch(void* const* d_in, const int* in_sizes, int n_in,
                              void* d_out, int out_size, void* d_ws, size_t ws_size,
                              hipStream_t stream) {
    const float* x  = (const float*)d_in[0];
    const int*   ei = (const int*)d_in[1];
    const float* W1 = (const float*)d_in[2];
    const float* g1 = (const float*)d_in[4];
    const float* be1= (const float*)d_in[5];
    const float* W2 = (const float*)d_in[6];
    const float* g2 = (const float*)d_in[8];
    const float* be2= (const float*)d_in[9];
    const float* W3 = (const float*)d_in[10];
    const float* g3 = (const float*)d_in[12];
    const float* be3= (const float*)d_in[13];
    const float* W4 = (const float*)d_in[14];
    const float* b4 = (const float*)d_in[15];
    float* out = (float*)d_out;

    const int N = in_sizes[0] / 128;
    const int E = in_sizes[1] / 2;
    const int* srcI = ei;
    const int* dstI = ei + E;
    const int NBc = cdiv(E, CCHUNK);           // edge chunks
    const int HN  = K_BUCK * NBc;              // histogram entries
    const int NBh = cdiv(HN, SCHUNK);          // scan blocks for hist

    char* p = (char*)d_ws;
    auto carve = [&](size_t bytes) {
        void* q = (void*)p;
        p += (bytes + 255) & ~(size_t)255;
        return q;
    };
    int*   offsets = (int*)  carve((size_t)(N + 1) * 4);
    float* dinv    = (float*)carve((size_t)N * 4);
    int*   csr_src = (int*)  carve((size_t)E * 4);
    int*   hist    = (int*)  carve((size_t)HN * 4);
    int*   hbase   = (int*)  carve((size_t)(HN + 1) * 4);
    int2*  ebuf    = (int2*) carve((size_t)E * 8);
    int*   bsum    = (int*)  carve((size_t)(NBh + 1) * 4);
    float* stats   = (float*)carve(384 * 4);   // L1@0 (2x16), L2@128 (2x32), L3@256 (2x64)
    float* A       = (float*)carve((size_t)N * 64 * 4);
    float* B       = (float*)carve((size_t)N * 64 * 4);

    // --- bucket-sort CSR build (coalesced writes; no global atomics) ---
    bucket_hist_kernel<<<NBc, TPB, 0, stream>>>(dstI, hist, stats, E, N, NBc);
    scan_reduce_kernel<<<NBh, TPB, 0, stream>>>(hist, bsum, HN);
    scan_bsum_kernel<<<1, 64, 0, stream>>>(bsum, NBh);
    scan_apply_kernel<<<NBh, TPB, 0, stream>>>(hist, bsum, hbase, HN);
    bucket_scatter_kernel<<<NBc, TPB, 0, stream>>>(srcI, dstI, hist, hbase, ebuf, E, N, NBc);
    bucket_offsets_kernel<<<K_BUCK, TPB, 0, stream>>>(ebuf, hbase, offsets, dinv, E, N, NBc);
    csr_fill_kernel<<<K_BUCK, TPB, 0, stream>>>(ebuf, hbase, offsets, csr_src, E, N, NBc);

    // --- L1: transform(128->16, prescaled) then aggregate(16) [stats fused] ---
    gemm4_kernel<128, 16, false, true><<<cdiv((long long)N * 4, TPB), TPB, 0, stream>>>(x, W1, A, nullptr, dinv, N);
    agg4_kernel<16, true><<<1024, TPB, 0, stream>>>(A, B, dinv, offsets, csr_src, stats + 0, N);
    bn_gelu_kernel<16, true><<<cdiv((long long)N * 16, TPB), TPB, 0, stream>>>(B, stats + 0, g1, be1, dinv, N);

    // --- L2: aggregate(16) then transform(16->32) [stats fused into gemm] ---
    agg4_kernel<16, false><<<cdiv((long long)N * 4, TPB), TPB, 0, stream>>>(B, A, dinv, offsets, csr_src, nullptr, N);
    gemm4_kernel<16, 32, true, false><<<cdiv((long long)N * 8, TPB), TPB, 0, stream>>>(A, W2, B, stats + 128, nullptr, N);
    bn_gelu_kernel<32, true><<<cdiv((long long)N * 32, TPB), TPB, 0, stream>>>(B, stats + 128, g2, be2, dinv, N);

    // --- L3: aggregate(32) then transform(32->64) [stats fused into gemm] ---
    agg4_kernel<32, false><<<cdiv((long long)N * 8, TPB), TPB, 0, stream>>>(B, A, dinv, offsets, csr_src, nullptr, N);
    gemm4_kernel<32, 64, true, false><<<cdiv((long long)N * 16, TPB), TPB, 0, stream>>>(A, W3, B, stats + 256, nullptr, N);
    bn_gelu_kernel<64, false><<<cdiv((long long)N * 64, TPB), TPB, 0, stream>>>(B, stats + 256, g3, be3, nullptr, N);

    // --- L4: transform(64->10, prescaled) then aggregate(10)+b4+log_softmax ---
    gemm_l4_kernel<<<cdiv((long long)N * 2, TPB), TPB, 0, stream>>>(B, W4, A, dinv, N);
    agg_lsm_kernel<<<cdiv((long long)N * 16, TPB), TPB, 0, stream>>>(A, dinv, offsets, csr_src, b4, out, N);
}

// Round 11
// 432.643 us; speedup vs baseline: 1.3447x; 1.3447x over previous
//
#include <hip/hip_runtime.h>
#include <math.h>

// GCN: 4x GCNConv (self-loops, sym-norm) + BN+GELU between, log_softmax at end.
// CSR (by dst) built per call; aggregation = atomic-free gather; aggregate on the
// narrow side of each layer (linearity); BN bias-cancellation drops b1..b3.
// R1: hierarchical scan, fused BN-stats, fused log_softmax. 806 -> 622 us.
// R4: dinv-prescale + unrolled gather. 622 -> 553 us.
// R6: bucket-sort CSR build, all writes coalesced. 553 -> 524 us.
// R7: count_kernel + N-scans deleted (per-bucket LDS degree count). 524 -> 450 us.
// R9: gemm 4-col tiles REGRESSED (450 -> 582): L3 gemm 55 -> 161 us. VALU-time
//     identical (6.6us) => pure added stall: 4x fewer threads + LDS staging +
//     barriers killed latency hiding. Broadcast loads were never the problem.
// R10: gemm_rw: one THREAD per ROW, acc[FOUT] in VGPRs, W read with wave-uniform
//     indices straight from global (compiler -> s_load, scalar K$), float4 row
//     loads + float4 stores, NO LDS / NO barriers. BN-stats split into a tiny
//     standalone pass (L2-resident input) so the gemm has no reduction tail.

#define TPB 256
#define K_BUCK 256
#define CCHUNK 4096   // edges per chunk in C1/C2 (stage = 32 KB LDS)
#define DCAP 8192     // per-bucket CSR LDS capacity (32 KB); mean 6250, +24 sigma
constexpr float BN_EPS = 1e-5f;

#define SCHUNK 2048  // elements per scan block (256 thr x 8)

__global__ void scan_reduce_kernel(const int* __restrict__ in, int* __restrict__ bsum, int n) {
    int base = blockIdx.x * SCHUNK;
    int s = 0;
    for (int j = threadIdx.x; j < SCHUNK; j += TPB) {
        int i = base + j;
        s += (i < n) ? in[i] : 0;
    }
#pragma unroll
    for (int d = 32; d; d >>= 1) s += __shfl_down(s, d);
    __shared__ int ws[TPB / 64];
    if ((threadIdx.x & 63) == 0) ws[threadIdx.x >> 6] = s;
    __syncthreads();
    if (threadIdx.x == 0) {
        int t = 0;
        for (int w = 0; w < TPB / 64; ++w) t += ws[w];
        bsum[blockIdx.x] = t;
    }
}

// single wave: exclusive-scan bsum[0..nb)
__global__ void scan_bsum_kernel(int* __restrict__ bsum, int nb) {
    __shared__ int carry;
    int lane = threadIdx.x;
    if (lane == 0) carry = 0;
    __syncthreads();
    for (int base = 0; base < nb; base += 64) {
        int i = base + lane;
        int v = (i < nb) ? bsum[i] : 0;
        int incl = v;
#pragma unroll
        for (int d = 1; d < 64; d <<= 1) {
            int u = __shfl_up(incl, d);
            if (lane >= d) incl += u;
        }
        if (i < nb) bsum[i] = carry + incl - v;
        int tot = __shfl(incl, 63);
        __syncthreads();
        if (lane == 0) carry += tot;
        __syncthreads();
    }
}

// block-local scan + apply block prefix
__global__ void scan_apply_kernel(const int* __restrict__ in, const int* __restrict__ bsum,
                                  int* __restrict__ out, int n) {
    int base = blockIdx.x * SCHUNK;
    int tid = threadIdx.x;
    int lane = tid & 63, wave = tid >> 6;
    int i0 = base + tid * 8;
    int v[8];
    int tsum = 0;
#pragma unroll
    for (int k = 0; k < 8; ++k) {
        int i = i0 + k;
        v[k] = (i < n) ? in[i] : 0;
        tsum += v[k];
    }
    int incl = tsum;
#pragma unroll
    for (int d = 1; d < 64; d <<= 1) {
        int u = __shfl_up(incl, d);
        if (lane >= d) incl += u;
    }
    int lexcl = incl - tsum;
    __shared__ int wsum[TPB / 64];
    if (lane == 63) wsum[wave] = incl;
    __syncthreads();
    int wbase = 0;
    for (int w = 0; w < wave; ++w) wbase += wsum[w];
    int off = bsum[blockIdx.x] + wbase + lexcl;
#pragma unroll
    for (int k = 0; k < 8; ++k) {
        int i = i0 + k;
        if (i < n) out[i] = off;
        off += v[k];
    }
}

// ---------------- bucket-sort CSR build (all writes coalesced) ----------------

// C1: per-chunk histogram over K_BUCK dst-buckets -> hist[bucket * nb + chunk].
// Block 0 also zeroes the BN stats accumulators (runs well before any stats use).
__global__ void bucket_hist_kernel(const int* __restrict__ dst, int* __restrict__ hist,
                                   float* __restrict__ stats, int e, int n, int nb) {
    __shared__ int lh[K_BUCK];
    for (int i = threadIdx.x; i < K_BUCK; i += TPB) lh[i] = 0;
    if (blockIdx.x == 0)
        for (int i = threadIdx.x; i < 384; i += TPB) stats[i] = 0.0f;
    __syncthreads();
    int base = blockIdx.x * CCHUNK;
    int end = min(base + CCHUNK, e);
    int div = (n + K_BUCK - 1) / K_BUCK;
    for (int i = base + threadIdx.x; i < end; i += TPB) atomicAdd(&lh[dst[i] / div], 1);
    __syncthreads();
    for (int b = threadIdx.x; b < K_BUCK; b += TPB) hist[b * nb + blockIdx.x] = lh[b];
}

// C2: re-read chunk, group edges by bucket in LDS, flush runs to ebuf with
// sequential (coalesced) writes. hbase = exclusive scan of hist (bucket-major).
__global__ void bucket_scatter_kernel(const int* __restrict__ src, const int* __restrict__ dst,
                                      const int* __restrict__ hist, const int* __restrict__ hbase,
                                      int2* __restrict__ ebuf, int e, int n, int nb) {
    __shared__ int lbase[K_BUCK];  // global base of this (chunk,bucket) run
    __shared__ int eoff[K_BUCK];   // exclusive local offset of bucket in stage
    __shared__ int lcur[K_BUCK];   // local cursor
    __shared__ int2 stage[CCHUNK];
    int t = threadIdx.x;  // TPB == K_BUCK
    int blk = blockIdx.x;
    int c = hist[t * nb + blk];
    lbase[t] = hbase[t * nb + blk];
    lcur[t] = 0;
    eoff[t] = c;
    __syncthreads();
    for (int d = 1; d < K_BUCK; d <<= 1) {  // inclusive scan of counts
        int v = (t >= d) ? eoff[t - d] : 0;
        __syncthreads();
        eoff[t] += v;
        __syncthreads();
    }
    eoff[t] -= c;  // exclusive
    __syncthreads();
    int base = blk * CCHUNK;
    int end = min(base + CCHUNK, e);
    int div = (n + K_BUCK - 1) / K_BUCK;
    for (int i = base + t; i < end; i += TPB) {
        int d = dst[i];
        int b = d / div;
        int p = atomicAdd(&lcur[b], 1);
        stage[eoff[b] + p] = make_int2(src[i], d);
    }
    __syncthreads();
    int cnt_here = end - base;
    for (int j = t; j < cnt_here; j += TPB) {
        int2 e2 = stage[j];
        int b = e2.y / div;
        ebuf[lbase[b] + (j - eoff[b])] = e2;  // coalesced within runs
    }
}

// R7: per-bucket degree count (LDS atomics) + local wave scan -> offsets,
// dinv written coalesced. Global prefix at bucket boundary = hbase[b*nb] (free).
__global__ void bucket_offsets_kernel(const int2* __restrict__ ebuf, const int* __restrict__ hbase,
                                      int* __restrict__ offsets, float* __restrict__ dinv,
                                      int e, int n, int nb) {
    __shared__ int lcnt[512];
    __shared__ int lexc[512];
    int b = blockIdx.x;
    int div = (n + K_BUCK - 1) / K_BUCK;
    int lo = b * div;
    int hi = min(lo + div, n);
    int nloc = hi - lo;
    int ebeg = hbase[b * nb];
    int eend = (b == K_BUCK - 1) ? e : hbase[(b + 1) * nb];
    for (int i = threadIdx.x; i < 512; i += TPB) lcnt[i] = 0;
    __syncthreads();
    for (int j = ebeg + threadIdx.x; j < eend; j += TPB)
        atomicAdd(&lcnt[ebuf[j].y - lo], 1);
    __syncthreads();
    if (threadIdx.x < 64) {  // wave 0: exclusive scan of lcnt[0..512)
        int l = threadIdx.x;
        int base = l * 8;
        int v[8];
        int tsum = 0;
#pragma unroll
        for (int k = 0; k < 8; ++k) { v[k] = lcnt[base + k]; tsum += v[k]; }
        int incl = tsum;
#pragma unroll
        for (int d = 1; d < 64; d <<= 1) {
            int u = __shfl_up(incl, d);
            if (l >= d) incl += u;
        }
        int off = incl - tsum;
#pragma unroll
        for (int k = 0; k < 8; ++k) { lexc[base + k] = off; off += v[k]; }
    }
    __syncthreads();
    for (int i = threadIdx.x; i < nloc; i += TPB) {
        offsets[lo + i] = ebeg + lexc[i];
        dinv[lo + i] = rsqrtf((float)(lcnt[i] + 1));  // +1 = self loop
    }
    if (b == K_BUCK - 1 && threadIdx.x == 0) offsets[n] = e;
}

// D: one block per bucket; build the bucket's CSR segment in LDS via local
// cursors (offsets - segbase), then stream it out as full coalesced lines.
__global__ void csr_fill_kernel(const int2* __restrict__ ebuf, const int* __restrict__ hbase,
                                const int* __restrict__ offsets, int* __restrict__ csr_src,
                                int e, int n, int nb) {
    __shared__ int lcur[400];
    __shared__ int lcsr[DCAP];
    int b = blockIdx.x;
    int div = (n + K_BUCK - 1) / K_BUCK;
    int lo = b * div;
    int hi = min(lo + div, n);
    int ebeg = hbase[b * nb];
    int eend = (b == K_BUCK - 1) ? e : hbase[(b + 1) * nb];
    int segbase = offsets[lo];
    int seglen = eend - ebeg;
    for (int i = threadIdx.x; i < hi - lo; i += TPB) lcur[i] = offsets[lo + i] - segbase;
    __syncthreads();
    for (int j = ebeg + threadIdx.x; j < eend; j += TPB) {
        int2 e2 = ebuf[j];
        int p = atomicAdd(&lcur[e2.y - lo], 1);
        if (p < DCAP) lcsr[p] = e2.x;
        else csr_src[segbase + p] = e2.x;  // overflow guard (statistically never)
    }
    __syncthreads();
    int lim = min(seglen, DCAP);
    for (int j = threadIdx.x; j < lim; j += TPB) csr_src[segbase + j] = lcsr[j];
}

// ---------------- dense transforms (R10: thread-per-row, scalar W) ----------------

// One thread per row: acc[FOUT] in VGPRs (independent chains -> high ILP even at
// low occupancy), row read as FIN/4 float4, W[(k)*FOUT+c] is wave-uniform ->
// scalar loads through K$. No LDS, no barriers. Optional dinv prescale on output.
template <int FIN, int FOUT, bool DINV>
__global__ void gemm_rw_kernel(const float* __restrict__ H, const float* __restrict__ W,
                               float* __restrict__ O, const float* __restrict__ dinv, int n) {
    int row = blockIdx.x * blockDim.x + threadIdx.x;
    if (row >= n) return;
    float acc[FOUT];
#pragma unroll
    for (int c = 0; c < FOUT; ++c) acc[c] = 0.0f;
    const float4* h4 = (const float4*)(H + (size_t)row * FIN);
#pragma unroll
    for (int k = 0; k < FIN / 4; ++k) {
        float4 h = h4[k];
        const float* w = W + (size_t)(4 * k) * FOUT;
#pragma unroll
        for (int c = 0; c < FOUT; ++c) {
            acc[c] = fmaf(h.x, w[c], acc[c]);
            acc[c] = fmaf(h.y, w[FOUT + c], acc[c]);
            acc[c] = fmaf(h.z, w[2 * FOUT + c], acc[c]);
            acc[c] = fmaf(h.w, w[3 * FOUT + c], acc[c]);
        }
    }
    float sc = DINV ? dinv[row] : 1.0f;
    float4* o4 = (float4*)(O + (size_t)row * FOUT);
#pragma unroll
    for (int c = 0; c < FOUT / 4; ++c)
        o4[c] = make_float4(acc[4 * c] * sc, acc[4 * c + 1] * sc,
                            acc[4 * c + 2] * sc, acc[4 * c + 3] * sc);
}

// L4: FIN=64 -> FOUT=10, prescaled by dinv. 2 threads/row, 5 cols each.
__global__ void gemm_l4_kernel(const float* __restrict__ H, const float* __restrict__ W,
                               float* __restrict__ O, const float* __restrict__ dinv, int n) {
    __shared__ float Ws[64 * 10];
    for (int i = threadIdx.x; i < 640; i += blockDim.x) Ws[i] = W[i];
    __syncthreads();
    int gid = blockIdx.x * blockDim.x + threadIdx.x;
    int row = gid >> 1;
    int c0 = (gid & 1) * 5;
    if (row >= n) return;
    float acc[5] = {0.f, 0.f, 0.f, 0.f, 0.f};
    const float4* h4 = (const float4*)(H + (size_t)row * 64);
#pragma unroll
    for (int k = 0; k < 16; ++k) {
        float4 h = h4[k];
        const float* w0 = &Ws[(4 * k) * 10 + c0];
#pragma unroll
        for (int c = 0; c < 5; ++c) {
            acc[c] = fmaf(h.x, w0[c], acc[c]);
            acc[c] = fmaf(h.y, w0[10 + c], acc[c]);
            acc[c] = fmaf(h.z, w0[20 + c], acc[c]);
            acc[c] = fmaf(h.w, w0[30 + c], acc[c]);
        }
    }
    float sc = dinv[row];
#pragma unroll
    for (int c = 0; c < 5; ++c) O[(size_t)row * 10 + c0 + c] = acc[c] * sc;
}

// Standalone BN stats: per-feature sum & sumsq over V[n,F] (L2-resident).
template <int F>
__global__ void bn_stats_kernel(const float* __restrict__ V, float* __restrict__ stats, int n) {
    constexpr int RPB = TPB / F;
    int f = threadIdx.x % F;
    int rl = threadIdx.x / F;
    float s = 0.0f, s2 = 0.0f;
    for (int r = blockIdx.x * RPB + rl; r < n; r += gridDim.x * RPB) {
        float v = V[(size_t)r * F + f];
        s += v;
        s2 = fmaf(v, v, s2);
    }
    __shared__ float sh[2 * F];
    for (int i = threadIdx.x; i < 2 * F; i += TPB) sh[i] = 0.0f;
    __syncthreads();
    atomicAdd(&sh[f], s);
    atomicAdd(&sh[F + f], s2);
    __syncthreads();
    for (int i = threadIdx.x; i < 2 * F; i += TPB) atomicAdd(&stats[i], sh[i]);
}

// ---------------- aggregation ----------------

// Gather-aggregate over dinv-PRESCALED table T' (T'[u] = T[u]*dinv[u]):
//   out[node] = dinv[node] * (sum_{u in nbr} T'[u] + T'[node])
// Inner loop is pure gather+add, unrolled x4 for MLP. F%4==0: F/4 lanes/node.
template <int F, bool STATS>
__global__ void agg4_kernel(const float* __restrict__ T, float* __restrict__ A,
                            const float* __restrict__ dinv, const int* __restrict__ offsets,
                            const int* __restrict__ csr_src, float* __restrict__ stats, int n) {
    constexpr int G = F / 4;
    __shared__ float sh[STATS ? 2 * F : 1];
    if (STATS) {
        for (int i = threadIdx.x; i < 2 * F; i += blockDim.x) sh[i] = 0.0f;
        __syncthreads();
    }
    const float4* T4 = (const float4*)T;
    float4 ss = {0, 0, 0, 0}, s2 = {0, 0, 0, 0};
    int lane0 = -1;
    int total = n * G;
    int stride = gridDim.x * blockDim.x;  // % G == 0 since TPB % G == 0
    for (int idx = blockIdx.x * blockDim.x + threadIdx.x; idx < total; idx += stride) {
        int node = idx / G;
        int lane = idx % G;
        float4 acc = T4[(size_t)node * G + lane];  // self term (prescaled)
        int s = offsets[node], e = offsets[node + 1];
        int j = s;
        for (; j + 3 < e; j += 4) {
            int u0 = csr_src[j], u1 = csr_src[j + 1], u2 = csr_src[j + 2], u3 = csr_src[j + 3];
            float4 t0 = T4[(size_t)u0 * G + lane];
            float4 t1 = T4[(size_t)u1 * G + lane];
            float4 t2 = T4[(size_t)u2 * G + lane];
            float4 t3 = T4[(size_t)u3 * G + lane];
            acc.x += (t0.x + t1.x) + (t2.x + t3.x);
            acc.y += (t0.y + t1.y) + (t2.y + t3.y);
            acc.z += (t0.z + t1.z) + (t2.z + t3.z);
            acc.w += (t0.w + t1.w) + (t2.w + t3.w);
        }
        for (; j < e; ++j) {
            int u = csr_src[j];
            float4 t = T4[(size_t)u * G + lane];
            acc.x += t.x; acc.y += t.y; acc.z += t.z; acc.w += t.w;
        }
        float di = dinv[node];
        acc.x *= di; acc.y *= di; acc.z *= di; acc.w *= di;
        ((float4*)A)[(size_t)idx] = acc;
        if (STATS) {
            ss.x += acc.x; ss.y += acc.y; ss.z += acc.z; ss.w += acc.w;
            s2.x = fmaf(acc.x, acc.x, s2.x); s2.y = fmaf(acc.y, acc.y, s2.y);
            s2.z = fmaf(acc.z, acc.z, s2.z); s2.w = fmaf(acc.w, acc.w, s2.w);
            lane0 = lane;
        }
    }
    if (STATS) {
        if (lane0 >= 0) {
            atomicAdd(&sh[lane0 * 4 + 0], ss.x); atomicAdd(&sh[lane0 * 4 + 1], ss.y);
            atomicAdd(&sh[lane0 * 4 + 2], ss.z); atomicAdd(&sh[lane0 * 4 + 3], ss.w);
            atomicAdd(&sh[F + lane0 * 4 + 0], s2.x); atomicAdd(&sh[F + lane0 * 4 + 1], s2.y);
            atomicAdd(&sh[F + lane0 * 4 + 2], s2.z); atomicAdd(&sh[F + lane0 * 4 + 3], s2.w);
        }
        __syncthreads();
        for (int i = threadIdx.x; i < 2 * F; i += blockDim.x) atomicAdd(&stats[i], sh[i]);
    }
}

// Final layer: aggregate prescaled F=10 (16 lanes/node) + b4 + log_softmax.
__global__ void agg_lsm_kernel(const float* __restrict__ T, const float* __restrict__ dinv,
                               const int* __restrict__ offsets, const int* __restrict__ csr_src,
                               const float* __restrict__ b4, float* __restrict__ out, int n) {
    int idx = blockIdx.x * blockDim.x + threadIdx.x;
    int node = idx >> 4;
    int lane = idx & 15;
    if (node >= n) return;
    bool act = lane < 10;
    float acc = act ? T[(size_t)node * 10 + lane] : 0.0f;  // self (prescaled)
    int s = offsets[node], e = offsets[node + 1];
    int j = s;
    for (; j + 1 < e; j += 2) {
        int u0 = csr_src[j], u1 = csr_src[j + 1];
        float t0 = act ? T[(size_t)u0 * 10 + lane] : 0.0f;
        float t1 = act ? T[(size_t)u1 * 10 + lane] : 0.0f;
        acc += t0 + t1;
    }
    if (j < e) {
        int u = csr_src[j];
        if (act) acc += T[(size_t)u * 10 + lane];
    }
    float v = act ? fmaf(dinv[node], acc, b4[lane]) : -1e30f;
    float m = v;
#pragma unroll
    for (int d = 1; d < 16; d <<= 1) m = fmaxf(m, __shfl_xor(m, d));
    float ex = act ? expf(v - m) : 0.0f;
    float sum = ex;
#pragma unroll
    for (int d = 1; d < 16; d <<= 1) sum += __shfl_xor(sum, d);
    if (act) out[(size_t)node * 10 + lane] = v - m - logf(sum);
}

// ---------------- BN + GELU ----------------

// In-place BN (batch stats) + exact GELU; optional prescale by dinv (next-agg fusion).
template <int F, bool DINV>
__global__ void bn_gelu_kernel(float* __restrict__ V, const float* __restrict__ stats,
                               const float* __restrict__ g, const float* __restrict__ be,
                               const float* __restrict__ dinv, int n) {
    int i = blockIdx.x * blockDim.x + threadIdx.x;
    if (i >= n * F) return;
    int f = i % F;
    float inv_n = 1.0f / (float)n;
    float mu = stats[f] * inv_n;
    float var = stats[F + f] * inv_n - mu * mu;
    float sc = rsqrtf(var + BN_EPS) * g[f];
    float shf = be[f] - mu * sc;
    float x = fmaf(V[i], sc, shf);
    float y = 0.5f * x * (1.0f + erff(x * 0.70710678118654752f));
    V[i] = DINV ? y * dinv[i / F] : y;
}

static inline int cdiv(long long a, int b) { return (int)((a + b - 1) / b); }

extern "C" void kernel_launch(void* const* d_in, const int* in_sizes, int n_in,
                              void* d_out, int out_size, void* d_ws, size_t ws_size,
                              hipStream_t stream) {
    const float* x  = (const float*)d_in[0];
    const int*   ei = (const int*)d_in[1];
    const float* W1 = (const float*)d_in[2];
    const float* g1 = (const float*)d_in[4];
    const float* be1= (const float*)d_in[5];
    const float* W2 = (const float*)d_in[6];
    const float* g2 = (const float*)d_in[8];
    const float* be2= (const float*)d_in[9];
    const float* W3 = (const float*)d_in[10];
    const float* g3 = (const float*)d_in[12];
    const float* be3= (const float*)d_in[13];
    const float* W4 = (const float*)d_in[14];
    const float* b4 = (const float*)d_in[15];
    float* out = (float*)d_out;

    const int N = in_sizes[0] / 128;
    const int E = in_sizes[1] / 2;
    const int* srcI = ei;
    const int* dstI = ei + E;
    const int NBc = cdiv(E, CCHUNK);           // edge chunks
    const int HN  = K_BUCK * NBc;              // histogram entries
    const int NBh = cdiv(HN, SCHUNK);          // scan blocks for hist

    char* p = (char*)d_ws;
    auto carve = [&](size_t bytes) {
        void* q = (void*)p;
        p += (bytes + 255) & ~(size_t)255;
        return q;
    };
    int*   offsets = (int*)  carve((size_t)(N + 1) * 4);
    float* dinv    = (float*)carve((size_t)N * 4);
    int*   csr_src = (int*)  carve((size_t)E * 4);
    int*   hist    = (int*)  carve((size_t)HN * 4);
    int*   hbase   = (int*)  carve((size_t)(HN + 1) * 4);
    int2*  ebuf    = (int2*) carve((size_t)E * 8);
    int*   bsum    = (int*)  carve((size_t)(NBh + 1) * 4);
    float* stats   = (float*)carve(384 * 4);   // L1@0 (2x16), L2@128 (2x32), L3@256 (2x64)
    float* A       = (float*)carve((size_t)N * 64 * 4);
    float* B       = (float*)carve((size_t)N * 64 * 4);

    // --- bucket-sort CSR build (coalesced writes; no global atomics) ---
    bucket_hist_kernel<<<NBc, TPB, 0, stream>>>(dstI, hist, stats, E, N, NBc);
    scan_reduce_kernel<<<NBh, TPB, 0, stream>>>(hist, bsum, HN);
    scan_bsum_kernel<<<1, 64, 0, stream>>>(bsum, NBh);
    scan_apply_kernel<<<NBh, TPB, 0, stream>>>(hist, bsum, hbase, HN);
    bucket_scatter_kernel<<<NBc, TPB, 0, stream>>>(srcI, dstI, hist, hbase, ebuf, E, N, NBc);
    bucket_offsets_kernel<<<K_BUCK, TPB, 0, stream>>>(ebuf, hbase, offsets, dinv, E, N, NBc);
    csr_fill_kernel<<<K_BUCK, TPB, 0, stream>>>(ebuf, hbase, offsets, csr_src, E, N, NBc);

    // --- L1: transform(128->16, prescaled) then aggregate(16) [stats fused in agg] ---
    gemm_rw_kernel<128, 16, true><<<cdiv(N, TPB), TPB, 0, stream>>>(x, W1, A, dinv, N);
    agg4_kernel<16, true><<<1024, TPB, 0, stream>>>(A, B, dinv, offsets, csr_src, stats + 0, N);
    bn_gelu_kernel<16, true><<<cdiv((long long)N * 16, TPB), TPB, 0, stream>>>(B, stats + 0, g1, be1, dinv, N);

    // --- L2: aggregate(16) then transform(16->32), standalone stats ---
    agg4_kernel<16, false><<<cdiv((long long)N * 4, TPB), TPB, 0, stream>>>(B, A, dinv, offsets, csr_src, nullptr, N);
    gemm_rw_kernel<16, 32, false><<<cdiv(N, TPB), TPB, 0, stream>>>(A, W2, B, nullptr, N);
    bn_stats_kernel<32><<<256, TPB, 0, stream>>>(B, stats + 128, N);
    bn_gelu_kernel<32, true><<<cdiv((long long)N * 32, TPB), TPB, 0, stream>>>(B, stats + 128, g2, be2, dinv, N);

    // --- L3: aggregate(32) then transform(32->64), standalone stats ---
    agg4_kernel<32, false><<<cdiv((long long)N * 8, TPB), TPB, 0, stream>>>(B, A, dinv, offsets, csr_src, nullptr, N);
    gemm_rw_kernel<32, 64, false><<<cdiv(N, TPB), TPB, 0, stream>>>(A, W3, B, nullptr, N);
    bn_stats_kernel<64><<<256, TPB, 0, stream>>>(B, stats + 256, N);
    bn_gelu_kernel<64, false><<<cdiv((long long)N * 64, TPB), TPB, 0, stream>>>(B, stats + 256, g3, be3, nullptr, N);

    // --- L4: transform(64->10, prescaled) then aggregate(10)+b4+log_softmax ---
    gemm_l4_kernel<<<cdiv((long long)N * 2, TPB), TPB, 0, stream>>>(B, W4, A, dinv, N);
    agg_lsm_kernel<<<cdiv((long long)N * 16, TPB), TPB, 0, stream>>>(A, dinv, offsets, csr_src, b4, out, N);
}

// Round 12
// 411.224 us; speedup vs baseline: 1.4147x; 1.0521x over previous
//
#include <hip/hip_runtime.h>
#include <math.h>

// GCN: 4x GCNConv (self-loops, sym-norm) + BN+GELU between, log_softmax at end.
// CSR (by dst) built per call; aggregation = atomic-free gather; aggregate on the
// narrow side of each layer (linearity); BN bias-cancellation drops b1..b3.
// R1: hierarchical scan, fused BN-stats, fused log_softmax. 806 -> 622 us.
// R4: dinv-prescale + unrolled gather. 622 -> 553 us.
// R6: bucket-sort CSR build, all writes coalesced. 553 -> 524 us.
// R7: count_kernel + N-scans deleted (per-bucket LDS degree count). 524 -> 450 us.
// R9: gemm 4-col tiles REGRESSED (450 -> 582): fewer threads + barriers = stalls.
// R10: thread-per-row gemm (VGPR acc, scalar-K$ W, no LDS/barriers). 582 -> 433 us.
// R11: agg_lsm was #1 (42us, FETCH 29MB vs 11 ideal): 40B rows straddle 64B lines,
//      10 predicated scalar gathers/edge. Fix: pad L4 table to 16 floats = 1 line,
//      4 lanes/node x float4 gather (every fetched line = exactly one row).

#define TPB 256
#define K_BUCK 256
#define CCHUNK 4096   // edges per chunk in C1/C2 (stage = 32 KB LDS)
#define DCAP 8192     // per-bucket CSR LDS capacity (32 KB); mean 6250, +24 sigma
constexpr float BN_EPS = 1e-5f;

#define SCHUNK 2048  // elements per scan block (256 thr x 8)

__global__ void scan_reduce_kernel(const int* __restrict__ in, int* __restrict__ bsum, int n) {
    int base = blockIdx.x * SCHUNK;
    int s = 0;
    for (int j = threadIdx.x; j < SCHUNK; j += TPB) {
        int i = base + j;
        s += (i < n) ? in[i] : 0;
    }
#pragma unroll
    for (int d = 32; d; d >>= 1) s += __shfl_down(s, d);
    __shared__ int ws[TPB / 64];
    if ((threadIdx.x & 63) == 0) ws[threadIdx.x >> 6] = s;
    __syncthreads();
    if (threadIdx.x == 0) {
        int t = 0;
        for (int w = 0; w < TPB / 64; ++w) t += ws[w];
        bsum[blockIdx.x] = t;
    }
}

// single wave: exclusive-scan bsum[0..nb)
__global__ void scan_bsum_kernel(int* __restrict__ bsum, int nb) {
    __shared__ int carry;
    int lane = threadIdx.x;
    if (lane == 0) carry = 0;
    __syncthreads();
    for (int base = 0; base < nb; base += 64) {
        int i = base + lane;
        int v = (i < nb) ? bsum[i] : 0;
        int incl = v;
#pragma unroll
        for (int d = 1; d < 64; d <<= 1) {
            int u = __shfl_up(incl, d);
            if (lane >= d) incl += u;
        }
        if (i < nb) bsum[i] = carry + incl - v;
        int tot = __shfl(incl, 63);
        __syncthreads();
        if (lane == 0) carry += tot;
        __syncthreads();
    }
}

// block-local scan + apply block prefix
__global__ void scan_apply_kernel(const int* __restrict__ in, const int* __restrict__ bsum,
                                  int* __restrict__ out, int n) {
    int base = blockIdx.x * SCHUNK;
    int tid = threadIdx.x;
    int lane = tid & 63, wave = tid >> 6;
    int i0 = base + tid * 8;
    int v[8];
    int tsum = 0;
#pragma unroll
    for (int k = 0; k < 8; ++k) {
        int i = i0 + k;
        v[k] = (i < n) ? in[i] : 0;
        tsum += v[k];
    }
    int incl = tsum;
#pragma unroll
    for (int d = 1; d < 64; d <<= 1) {
        int u = __shfl_up(incl, d);
        if (lane >= d) incl += u;
    }
    int lexcl = incl - tsum;
    __shared__ int wsum[TPB / 64];
    if (lane == 63) wsum[wave] = incl;
    __syncthreads();
    int wbase = 0;
    for (int w = 0; w < wave; ++w) wbase += wsum[w];
    int off = bsum[blockIdx.x] + wbase + lexcl;
#pragma unroll
    for (int k = 0; k < 8; ++k) {
        int i = i0 + k;
        if (i < n) out[i] = off;
        off += v[k];
    }
}

// ---------------- bucket-sort CSR build (all writes coalesced) ----------------

// C1: per-chunk histogram over K_BUCK dst-buckets -> hist[bucket * nb + chunk].
// Block 0 also zeroes the BN stats accumulators (runs well before any stats use).
__global__ void bucket_hist_kernel(const int* __restrict__ dst, int* __restrict__ hist,
                                   float* __restrict__ stats, int e, int n, int nb) {
    __shared__ int lh[K_BUCK];
    for (int i = threadIdx.x; i < K_BUCK; i += TPB) lh[i] = 0;
    if (blockIdx.x == 0)
        for (int i = threadIdx.x; i < 384; i += TPB) stats[i] = 0.0f;
    __syncthreads();
    int base = blockIdx.x * CCHUNK;
    int end = min(base + CCHUNK, e);
    int div = (n + K_BUCK - 1) / K_BUCK;
    for (int i = base + threadIdx.x; i < end; i += TPB) atomicAdd(&lh[dst[i] / div], 1);
    __syncthreads();
    for (int b = threadIdx.x; b < K_BUCK; b += TPB) hist[b * nb + blockIdx.x] = lh[b];
}

// C2: re-read chunk, group edges by bucket in LDS, flush runs to ebuf with
// sequential (coalesced) writes. hbase = exclusive scan of hist (bucket-major).
__global__ void bucket_scatter_kernel(const int* __restrict__ src, const int* __restrict__ dst,
                                      const int* __restrict__ hist, const int* __restrict__ hbase,
                                      int2* __restrict__ ebuf, int e, int n, int nb) {
    __shared__ int lbase[K_BUCK];  // global base of this (chunk,bucket) run
    __shared__ int eoff[K_BUCK];   // exclusive local offset of bucket in stage
    __shared__ int lcur[K_BUCK];   // local cursor
    __shared__ int2 stage[CCHUNK];
    int t = threadIdx.x;  // TPB == K_BUCK
    int blk = blockIdx.x;
    int c = hist[t * nb + blk];
    lbase[t] = hbase[t * nb + blk];
    lcur[t] = 0;
    eoff[t] = c;
    __syncthreads();
    for (int d = 1; d < K_BUCK; d <<= 1) {  // inclusive scan of counts
        int v = (t >= d) ? eoff[t - d] : 0;
        __syncthreads();
        eoff[t] += v;
        __syncthreads();
    }
    eoff[t] -= c;  // exclusive
    __syncthreads();
    int base = blk * CCHUNK;
    int end = min(base + CCHUNK, e);
    int div = (n + K_BUCK - 1) / K_BUCK;
    for (int i = base + t; i < end; i += TPB) {
        int d = dst[i];
        int b = d / div;
        int p = atomicAdd(&lcur[b], 1);
        stage[eoff[b] + p] = make_int2(src[i], d);
    }
    __syncthreads();
    int cnt_here = end - base;
    for (int j = t; j < cnt_here; j += TPB) {
        int2 e2 = stage[j];
        int b = e2.y / div;
        ebuf[lbase[b] + (j - eoff[b])] = e2;  // coalesced within runs
    }
}

// R7: per-bucket degree count (LDS atomics) + local wave scan -> offsets,
// dinv written coalesced. Global prefix at bucket boundary = hbase[b*nb] (free).
__global__ void bucket_offsets_kernel(const int2* __restrict__ ebuf, const int* __restrict__ hbase,
                                      int* __restrict__ offsets, float* __restrict__ dinv,
                                      int e, int n, int nb) {
    __shared__ int lcnt[512];
    __shared__ int lexc[512];
    int b = blockIdx.x;
    int div = (n + K_BUCK - 1) / K_BUCK;
    int lo = b * div;
    int hi = min(lo + div, n);
    int nloc = hi - lo;
    int ebeg = hbase[b * nb];
    int eend = (b == K_BUCK - 1) ? e : hbase[(b + 1) * nb];
    for (int i = threadIdx.x; i < 512; i += TPB) lcnt[i] = 0;
    __syncthreads();
    for (int j = ebeg + threadIdx.x; j < eend; j += TPB)
        atomicAdd(&lcnt[ebuf[j].y - lo], 1);
    __syncthreads();
    if (threadIdx.x < 64) {  // wave 0: exclusive scan of lcnt[0..512)
        int l = threadIdx.x;
        int base = l * 8;
        int v[8];
        int tsum = 0;
#pragma unroll
        for (int k = 0; k < 8; ++k) { v[k] = lcnt[base + k]; tsum += v[k]; }
        int incl = tsum;
#pragma unroll
        for (int d = 1; d < 64; d <<= 1) {
            int u = __shfl_up(incl, d);
            if (l >= d) incl += u;
        }
        int off = incl - tsum;
#pragma unroll
        for (int k = 0; k < 8; ++k) { lexc[base + k] = off; off += v[k]; }
    }
    __syncthreads();
    for (int i = threadIdx.x; i < nloc; i += TPB) {
        offsets[lo + i] = ebeg + lexc[i];
        dinv[lo + i] = rsqrtf((float)(lcnt[i] + 1));  // +1 = self loop
    }
    if (b == K_BUCK - 1 && threadIdx.x == 0) offsets[n] = e;
}

// D: one block per bucket; build the bucket's CSR segment in LDS via local
// cursors (offsets - segbase), then stream it out as full coalesced lines.
__global__ void csr_fill_kernel(const int2* __restrict__ ebuf, const int* __restrict__ hbase,
                                const int* __restrict__ offsets, int* __restrict__ csr_src,
                                int e, int n, int nb) {
    __shared__ int lcur[400];
    __shared__ int lcsr[DCAP];
    int b = blockIdx.x;
    int div = (n + K_BUCK - 1) / K_BUCK;
    int lo = b * div;
    int hi = min(lo + div, n);
    int ebeg = hbase[b * nb];
    int eend = (b == K_BUCK - 1) ? e : hbase[(b + 1) * nb];
    int segbase = offsets[lo];
    int seglen = eend - ebeg;
    for (int i = threadIdx.x; i < hi - lo; i += TPB) lcur[i] = offsets[lo + i] - segbase;
    __syncthreads();
    for (int j = ebeg + threadIdx.x; j < eend; j += TPB) {
        int2 e2 = ebuf[j];
        int p = atomicAdd(&lcur[e2.y - lo], 1);
        if (p < DCAP) lcsr[p] = e2.x;
        else csr_src[segbase + p] = e2.x;  // overflow guard (statistically never)
    }
    __syncthreads();
    int lim = min(seglen, DCAP);
    for (int j = threadIdx.x; j < lim; j += TPB) csr_src[segbase + j] = lcsr[j];
}

// ---------------- dense transforms (R10: thread-per-row, scalar W) ----------------

// One thread per row: acc[FOUT] in VGPRs (independent chains -> high ILP even at
// low occupancy), row read as FIN/4 float4, W[(k)*FOUT+c] is wave-uniform ->
// scalar loads through K$. No LDS, no barriers. Optional dinv prescale on output.
template <int FIN, int FOUT, bool DINV>
__global__ void gemm_rw_kernel(const float* __restrict__ H, const float* __restrict__ W,
                               float* __restrict__ O, const float* __restrict__ dinv, int n) {
    int row = blockIdx.x * blockDim.x + threadIdx.x;
    if (row >= n) return;
    float acc[FOUT];
#pragma unroll
    for (int c = 0; c < FOUT; ++c) acc[c] = 0.0f;
    const float4* h4 = (const float4*)(H + (size_t)row * FIN);
#pragma unroll
    for (int k = 0; k < FIN / 4; ++k) {
        float4 h = h4[k];
        const float* w = W + (size_t)(4 * k) * FOUT;
#pragma unroll
        for (int c = 0; c < FOUT; ++c) {
            acc[c] = fmaf(h.x, w[c], acc[c]);
            acc[c] = fmaf(h.y, w[FOUT + c], acc[c]);
            acc[c] = fmaf(h.z, w[2 * FOUT + c], acc[c]);
            acc[c] = fmaf(h.w, w[3 * FOUT + c], acc[c]);
        }
    }
    float sc = DINV ? dinv[row] : 1.0f;
    float4* o4 = (float4*)(O + (size_t)row * FOUT);
#pragma unroll
    for (int c = 0; c < FOUT / 4; ++c)
        o4[c] = make_float4(acc[4 * c] * sc, acc[4 * c + 1] * sc,
                            acc[4 * c + 2] * sc, acc[4 * c + 3] * sc);
}

// L4: FIN=64 -> FOUT=10 (stored at stride 16 = one 64B line/row), prescaled.
// One thread per row, 10 acc in VGPRs, aligned float4 stores (pads unwritten).
__global__ void gemm_l4_kernel(const float* __restrict__ H, const float* __restrict__ W,
                               float* __restrict__ O, const float* __restrict__ dinv, int n) {
    int row = blockIdx.x * blockDim.x + threadIdx.x;
    if (row >= n) return;
    float acc[10];
#pragma unroll
    for (int c = 0; c < 10; ++c) acc[c] = 0.0f;
    const float4* h4 = (const float4*)(H + (size_t)row * 64);
#pragma unroll
    for (int k = 0; k < 16; ++k) {
        float4 h = h4[k];
        const float* w = W + (size_t)(4 * k) * 10;
#pragma unroll
        for (int c = 0; c < 10; ++c) {
            acc[c] = fmaf(h.x, w[c], acc[c]);
            acc[c] = fmaf(h.y, w[10 + c], acc[c]);
            acc[c] = fmaf(h.z, w[20 + c], acc[c]);
            acc[c] = fmaf(h.w, w[30 + c], acc[c]);
        }
    }
    float sc = dinv[row];
    float4* o4 = (float4*)(O + (size_t)row * 16);
    o4[0] = make_float4(acc[0] * sc, acc[1] * sc, acc[2] * sc, acc[3] * sc);
    o4[1] = make_float4(acc[4] * sc, acc[5] * sc, acc[6] * sc, acc[7] * sc);
    o4[2] = make_float4(acc[8] * sc, acc[9] * sc, 0.0f, 0.0f);
}

// Standalone BN stats: per-feature sum & sumsq over V[n,F] (L2-resident).
template <int F>
__global__ void bn_stats_kernel(const float* __restrict__ V, float* __restrict__ stats, int n) {
    constexpr int RPB = TPB / F;
    int f = threadIdx.x % F;
    int rl = threadIdx.x / F;
    float s = 0.0f, s2 = 0.0f;
    for (int r = blockIdx.x * RPB + rl; r < n; r += gridDim.x * RPB) {
        float v = V[(size_t)r * F + f];
        s += v;
        s2 = fmaf(v, v, s2);
    }
    __shared__ float sh[2 * F];
    for (int i = threadIdx.x; i < 2 * F; i += TPB) sh[i] = 0.0f;
    __syncthreads();
    atomicAdd(&sh[f], s);
    atomicAdd(&sh[F + f], s2);
    __syncthreads();
    for (int i = threadIdx.x; i < 2 * F; i += TPB) atomicAdd(&stats[i], sh[i]);
}

// ---------------- aggregation ----------------

// Gather-aggregate over dinv-PRESCALED table T' (T'[u] = T[u]*dinv[u]):
//   out[node] = dinv[node] * (sum_{u in nbr} T'[u] + T'[node])
// Inner loop is pure gather+add, unrolled x4 for MLP. F%4==0: F/4 lanes/node.
template <int F, bool STATS>
__global__ void agg4_kernel(const float* __restrict__ T, float* __restrict__ A,
                            const float* __restrict__ dinv, const int* __restrict__ offsets,
                            const int* __restrict__ csr_src, float* __restrict__ stats, int n) {
    constexpr int G = F / 4;
    __shared__ float sh[STATS ? 2 * F : 1];
    if (STATS) {
        for (int i = threadIdx.x; i < 2 * F; i += blockDim.x) sh[i] = 0.0f;
        __syncthreads();
    }
    const float4* T4 = (const float4*)T;
    float4 ss = {0, 0, 0, 0}, s2 = {0, 0, 0, 0};
    int lane0 = -1;
    int total = n * G;
    int stride = gridDim.x * blockDim.x;  // % G == 0 since TPB % G == 0
    for (int idx = blockIdx.x * blockDim.x + threadIdx.x; idx < total; idx += stride) {
        int node = idx / G;
        int lane = idx % G;
        float4 acc = T4[(size_t)node * G + lane];  // self term (prescaled)
        int s = offsets[node], e = offsets[node + 1];
        int j = s;
        for (; j + 3 < e; j += 4) {
            int u0 = csr_src[j], u1 = csr_src[j + 1], u2 = csr_src[j + 2], u3 = csr_src[j + 3];
            float4 t0 = T4[(size_t)u0 * G + lane];
            float4 t1 = T4[(size_t)u1 * G + lane];
            float4 t2 = T4[(size_t)u2 * G + lane];
            float4 t3 = T4[(size_t)u3 * G + lane];
            acc.x += (t0.x + t1.x) + (t2.x + t3.x);
            acc.y += (t0.y + t1.y) + (t2.y + t3.y);
            acc.z += (t0.z + t1.z) + (t2.z + t3.z);
            acc.w += (t0.w + t1.w) + (t2.w + t3.w);
        }
        for (; j < e; ++j) {
            int u = csr_src[j];
            float4 t = T4[(size_t)u * G + lane];
            acc.x += t.x; acc.y += t.y; acc.z += t.z; acc.w += t.w;
        }
        float di = dinv[node];
        acc.x *= di; acc.y *= di; acc.z *= di; acc.w *= di;
        ((float4*)A)[(size_t)idx] = acc;
        if (STATS) {
            ss.x += acc.x; ss.y += acc.y; ss.z += acc.z; ss.w += acc.w;
            s2.x = fmaf(acc.x, acc.x, s2.x); s2.y = fmaf(acc.y, acc.y, s2.y);
            s2.z = fmaf(acc.z, acc.z, s2.z); s2.w = fmaf(acc.w, acc.w, s2.w);
            lane0 = lane;
        }
    }
    if (STATS) {
        if (lane0 >= 0) {
            atomicAdd(&sh[lane0 * 4 + 0], ss.x); atomicAdd(&sh[lane0 * 4 + 1], ss.y);
            atomicAdd(&sh[lane0 * 4 + 2], ss.z); atomicAdd(&sh[lane0 * 4 + 3], ss.w);
            atomicAdd(&sh[F + lane0 * 4 + 0], s2.x); atomicAdd(&sh[F + lane0 * 4 + 1], s2.y);
            atomicAdd(&sh[F + lane0 * 4 + 2], s2.z); atomicAdd(&sh[F + lane0 * 4 + 3], s2.w);
        }
        __syncthreads();
        for (int i = threadIdx.x; i < 2 * F; i += blockDim.x) atomicAdd(&stats[i], sh[i]);
    }
}

// R11 final layer: T padded to 16 floats/row (one 64B line). 4 lanes/node, one
// float4 gather each; valid cols = 4*lane+j < 10; log_softmax via quad shfl_xor.
__global__ void agg_lsm_kernel(const float* __restrict__ T, const float* __restrict__ dinv,
                               const int* __restrict__ offsets, const int* __restrict__ csr_src,
                               const float* __restrict__ b4, float* __restrict__ out, int n) {
    int idx = blockIdx.x * blockDim.x + threadIdx.x;
    int node = idx >> 2;
    int lane = idx & 3;
    if (node >= n) return;
    const float4* T4 = (const float4*)T;
    float4 acc = T4[(size_t)node * 4 + lane];  // self (prescaled; pads garbage, masked later)
    int s = offsets[node], e = offsets[node + 1];
    int j = s;
    for (; j + 1 < e; j += 2) {
        int u0 = csr_src[j], u1 = csr_src[j + 1];
        float4 t0 = T4[(size_t)u0 * 4 + lane];
        float4 t1 = T4[(size_t)u1 * 4 + lane];
        acc.x += t0.x + t1.x; acc.y += t0.y + t1.y;
        acc.z += t0.z + t1.z; acc.w += t0.w + t1.w;
    }
    if (j < e) {
        int u = csr_src[j];
        float4 t = T4[(size_t)u * 4 + lane];
        acc.x += t.x; acc.y += t.y; acc.z += t.z; acc.w += t.w;
    }
    float di = dinv[node];
    int c0 = lane * 4;
    float v[4];
    int nv = (c0 < 10) ? min(10 - c0, 4) : 0;  // valid elems this lane
#pragma unroll
    for (int k = 0; k < 4; ++k) {
        float a = (k == 0) ? acc.x : (k == 1) ? acc.y : (k == 2) ? acc.z : acc.w;
        v[k] = (k < nv) ? fmaf(di, a, b4[c0 + k]) : -1e30f;
    }
    float m = fmaxf(fmaxf(v[0], v[1]), fmaxf(v[2], v[3]));
    m = fmaxf(m, __shfl_xor(m, 1));
    m = fmaxf(m, __shfl_xor(m, 2));
    float sum = 0.0f;
#pragma unroll
    for (int k = 0; k < 4; ++k)
        if (k < nv) sum += expf(v[k] - m);
    sum += __shfl_xor(sum, 1);
    sum += __shfl_xor(sum, 2);
    float ls = m + logf(sum);
#pragma unroll
    for (int k = 0; k < 4; ++k)
        if (k < nv) out[(size_t)node * 10 + c0 + k] = v[k] - ls;
}

// ---------------- BN + GELU ----------------

// In-place BN (batch stats) + exact GELU; optional prescale by dinv (next-agg fusion).
template <int F, bool DINV>
__global__ void bn_gelu_kernel(float* __restrict__ V, const float* __restrict__ stats,
                               const float* __restrict__ g, const float* __restrict__ be,
                               const float* __restrict__ dinv, int n) {
    int i = blockIdx.x * blockDim.x + threadIdx.x;
    if (i >= n * F) return;
    int f = i % F;
    float inv_n = 1.0f / (float)n;
    float mu = stats[f] * inv_n;
    float var = stats[F + f] * inv_n - mu * mu;
    float sc = rsqrtf(var + BN_EPS) * g[f];
    float shf = be[f] - mu * sc;
    float x = fmaf(V[i], sc, shf);
    float y = 0.5f * x * (1.0f + erff(x * 0.70710678118654752f));
    V[i] = DINV ? y * dinv[i / F] : y;
}

static inline int cdiv(long long a, int b) { return (int)((a + b - 1) / b); }

extern "C" void kernel_launch(void* const* d_in, const int* in_sizes, int n_in,
                              void* d_out, int out_size, void* d_ws, size_t ws_size,
                              hipStream_t stream) {
    const float* x  = (const float*)d_in[0];
    const int*   ei = (const int*)d_in[1];
    const float* W1 = (const float*)d_in[2];
    const float* g1 = (const float*)d_in[4];
    const float* be1= (const float*)d_in[5];
    const float* W2 = (const float*)d_in[6];
    const float* g2 = (const float*)d_in[8];
    const float* be2= (const float*)d_in[9];
    const float* W3 = (const float*)d_in[10];
    const float* g3 = (const float*)d_in[12];
    const float* be3= (const float*)d_in[13];
    const float* W4 = (const float*)d_in[14];
    const float* b4 = (const float*)d_in[15];
    float* out = (float*)d_out;

    const int N = in_sizes[0] / 128;
    const int E = in_sizes[1] / 2;
    const int* srcI = ei;
    const int* dstI = ei + E;
    const int NBc = cdiv(E, CCHUNK);           // edge chunks
    const int HN  = K_BUCK * NBc;              // histogram entries
    const int NBh = cdiv(HN, SCHUNK);          // scan blocks for hist

    char* p = (char*)d_ws;
    auto carve = [&](size_t bytes) {
        void* q = (void*)p;
        p += (bytes + 255) & ~(size_t)255;
        return q;
    };
    int*   offsets = (int*)  carve((size_t)(N + 1) * 4);
    float* dinv    = (float*)carve((size_t)N * 4);
    int*   csr_src = (int*)  carve((size_t)E * 4);
    int*   hist    = (int*)  carve((size_t)HN * 4);
    int*   hbase   = (int*)  carve((size_t)(HN + 1) * 4);
    int2*  ebuf    = (int2*) carve((size_t)E * 8);
    int*   bsum    = (int*)  carve((size_t)(NBh + 1) * 4);
    float* stats   = (float*)carve(384 * 4);   // L1@0 (2x16), L2@128 (2x32), L3@256 (2x64)
    float* A       = (float*)carve((size_t)N * 64 * 4);
    float* B       = (float*)carve((size_t)N * 64 * 4);

    // --- bucket-sort CSR build (coalesced writes; no global atomics) ---
    bucket_hist_kernel<<<NBc, TPB, 0, stream>>>(dstI, hist, stats, E, N, NBc);
    scan_reduce_kernel<<<NBh, TPB, 0, stream>>>(hist, bsum, HN);
    scan_bsum_kernel<<<1, 64, 0, stream>>>(bsum, NBh);
    scan_apply_kernel<<<NBh, TPB, 0, stream>>>(hist, bsum, hbase, HN);
    bucket_scatter_kernel<<<NBc, TPB, 0, stream>>>(srcI, dstI, hist, hbase, ebuf, E, N, NBc);
    bucket_offsets_kernel<<<K_BUCK, TPB, 0, stream>>>(ebuf, hbase, offsets, dinv, E, N, NBc);
    csr_fill_kernel<<<K_BUCK, TPB, 0, stream>>>(ebuf, hbase, offsets, csr_src, E, N, NBc);

    // --- L1: transform(128->16, prescaled) then aggregate(16) [stats fused in agg] ---
    gemm_rw_kernel<128, 16, true><<<cdiv(N, TPB), TPB, 0, stream>>>(x, W1, A, dinv, N);
    agg4_kernel<16, true><<<1024, TPB, 0, stream>>>(A, B, dinv, offsets, csr_src, stats + 0, N);
    bn_gelu_kernel<16, true><<<cdiv((long long)N * 16, TPB), TPB, 0, stream>>>(B, stats + 0, g1, be1, dinv, N);

    // --- L2: aggregate(16) then transform(16->32), standalone stats ---
    agg4_kernel<16, false><<<cdiv((long long)N * 4, TPB), TPB, 0, stream>>>(B, A, dinv, offsets, csr_src, nullptr, N);
    gemm_rw_kernel<16, 32, false><<<cdiv(N, TPB), TPB, 0, stream>>>(A, W2, B, nullptr, N);
    bn_stats_kernel<32><<<256, TPB, 0, stream>>>(B, stats + 128, N);
    bn_gelu_kernel<32, true><<<cdiv((long long)N * 32, TPB), TPB, 0, stream>>>(B, stats + 128, g2, be2, dinv, N);

    // --- L3: aggregate(32) then transform(32->64), standalone stats ---
    agg4_kernel<32, false><<<cdiv((long long)N * 8, TPB), TPB, 0, stream>>>(B, A, dinv, offsets, csr_src, nullptr, N);
    gemm_rw_kernel<32, 64, false><<<cdiv(N, TPB), TPB, 0, stream>>>(A, W3, B, nullptr, N);
    bn_stats_kernel<64><<<256, TPB, 0, stream>>>(B, stats + 256, N);
    bn_gelu_kernel<64, false><<<cdiv((long long)N * 64, TPB), TPB, 0, stream>>>(B, stats + 256, g3, be3, nullptr, N);

    // --- L4: transform(64->10 @stride16, prescaled) then agg(float4)+b4+lsm ---
    gemm_l4_kernel<<<cdiv(N, TPB), TPB, 0, stream>>>(B, W4, A, dinv, N);
    agg_lsm_kernel<<<cdiv((long long)N * 4, TPB), TPB, 0, stream>>>(A, dinv, offsets, csr_src, b4, out, N);
}